// Round 7
// baseline (415.919 us; speedup 1.0000x reference)
//
#include <hip/hip_runtime.h>
#include <math.h>

#define D 128
#define NBUCK_MAX 1024     // runtime nbuck = ceil(N/128) = 782
#define CAPB 4096          // edge slots per bucket (mean fill 2048, >22 sigma margin)
#define CAPS 1024          // slots per sub-cursor (4 subs per bucket)

typedef unsigned short u16;
typedef unsigned int   u32;
typedef __attribute__((ext_vector_type(8))) short short8;   // 8 bf16 = 4 VGPRs (MFMA A/B frag)
typedef __attribute__((ext_vector_type(4))) float f32x4;    // MFMA C/D frag
typedef __attribute__((ext_vector_type(2))) float f32x2;

static __device__ __forceinline__ u16 f32_to_bf16(float f) {
    u32 u = __builtin_bit_cast(u32, f);
    u32 r = (u + 0x7FFFu + ((u >> 16) & 1u)) >> 16;          // RNE
    return (u16)r;
}
static __device__ __forceinline__ u32 pack_bf16x2(float lo, float hi) {
    return (u32)f32_to_bf16(lo) | ((u32)f32_to_bf16(hi) << 16);
}
static __device__ __forceinline__ float bf16lo_to_f32(u32 v) {
    return __builtin_bit_cast(float, v << 16);
}
static __device__ __forceinline__ float bf16hi_to_f32(u32 v) {
    return __builtin_bit_cast(float, v & 0xFFFF0000u);
}

// ---------------- prep: goff scan (block 0) + cursor zero (block 1) + W pack (blocks 2..129) ----------------
// Wp[((nt*4+kt)*64 + lane)*8 + j] = bf16( W[kt*32 + (lane>>4)*8 + j][nt*16 + (lane&15)] )
__global__ __launch_bounds__(256) void prep(const float* __restrict__ W0, const float* __restrict__ W1,
                                            u16* __restrict__ Wp0, u16* __restrict__ Wp1,
                                            const int* __restrict__ gsz, int G, int* __restrict__ goff,
                                            u32* __restrict__ cursor, int ncur) {
    int b = blockIdx.x;
    int tid = threadIdx.x;
    if (b == 0) {
        // exclusive scan of graph sizes with sentinel goff[G]
        __shared__ int wsum[4];
        int base = tid * 4;
        int v[4];
        #pragma unroll
        for (int k = 0; k < 4; k++) v[k] = (base + k < G) ? gsz[base + k] : 0;
        int s = v[0] + v[1] + v[2] + v[3];
        int lane = tid & 63;
        int incl = s;
        #pragma unroll
        for (int off = 1; off < 64; off <<= 1) { int t = __shfl_up(incl, off); if (lane >= off) incl += t; }
        int wv = tid >> 6;
        if (lane == 63) wsum[wv] = incl;
        __syncthreads();
        int woff = 0;
        for (int w = 0; w < wv; w++) woff += wsum[w];
        int run = woff + incl - s;
        #pragma unroll
        for (int k = 0; k < 4; k++) {
            if (base + k <= G) goff[base + k] = run;
            run += v[k];
        }
    } else if (b == 1) {
        for (int i = tid; i < ncur; i += 256) cursor[i] = 0;
    } else {
        int gidx = (b - 2) * 256 + tid;                      // 0 .. 32767
        const float* W = (gidx < 128 * 128) ? W0 : W1;
        u16* Wp = (gidx < 128 * 128) ? Wp0 : Wp1;
        int idx = gidx & (128 * 128 - 1);
        int j = idx & 7, lane = (idx >> 3) & 63, kt = (idx >> 9) & 3, nt = idx >> 11;
        int k = kt * 32 + ((lane >> 4) << 3) + j;
        int n = nt * 16 + (lane & 15);
        Wp[idx] = f32_to_bf16(W[k * 128 + n]);
    }
}

// ---------------- single-pass bucket placement: global atomic sub-cursors, static bucket bases ----------------
// packed edge = src | (dstLocal << 20); bucket region [b*CAPB, (b+1)*CAPB), sub s owns [s*CAPS, (s+1)*CAPS)
__global__ __launch_bounds__(512) void bucket_place(const int* __restrict__ src, const int* __restrict__ dst,
                                                    int E, u32* __restrict__ cursor, u32* __restrict__ edgeBuf) {
    int stride = gridDim.x * 512;
    int sub = threadIdx.x & 3;
    for (int i = blockIdx.x * 512 + threadIdx.x; i < E; i += stride) {
        int d = dst[i];
        int b = d >> 7;
        u32 pos = atomicAdd(&cursor[b * 4 + sub], 1);
        if (pos < CAPS)
            edgeBuf[((size_t)b << 12) + (sub << 10) + pos] = (u32)src[i] | ((u32)(d & 127) << 20);
    }
}

// ---------------- fused: csr_finalize (blocks 0..nbuck-1) + gemm layer0 (blocks nbuck..) ----------------
// finalize: per-bucket LDS counting sort -> col_idx (padded layout) + rowse[node]={start,end}
// gemm0: reads fp32 X (in-register bf16 cast), MFMA, writes bf16 xwb (row N = zero pad row)

static __device__ __forceinline__ void gemm_body(const short8 af[4], const u16* __restrict__ Wp,
                                                 u16* __restrict__ outb, int N, int row0,
                                                 int tid, int wave, int lane, int quad, int l16,
                                                 u16* Cs) {
    f32x4 acc[8];
    #pragma unroll
    for (int nt = 0; nt < 8; nt++) acc[nt] = (f32x4){0.f, 0.f, 0.f, 0.f};
    #pragma unroll
    for (int kt = 0; kt < 4; kt++) {
        #pragma unroll
        for (int nt = 0; nt < 8; nt++) {
            short8 bf = *(const short8*)(Wp + ((size_t)(nt * 4 + kt) * 64 + lane) * 8);
            acc[nt] = __builtin_amdgcn_mfma_f32_16x16x32_bf16(af[kt], bf, acc[nt], 0, 0, 0);
        }
    }
    // C layout col=lane&15, row=quad*4+reg -> LDS transpose -> coalesced bf16 store
    #pragma unroll
    for (int nt = 0; nt < 8; nt++) {
        #pragma unroll
        for (int r = 0; r < 4; r++) {
            int rl = wave * 16 + quad * 4 + r;
            Cs[rl * 136 + nt * 16 + l16] = f32_to_bf16(acc[nt][r]);
        }
    }
    __syncthreads();
    for (int i = tid; i < 64 * 16; i += 256) {
        int row = i >> 4, chunk = i & 15;
        int grow = row0 + row;
        if (grow <= N)      // row N = zero pad row for agg tail lanes
            *(uint4*)(outb + (size_t)grow * 128 + chunk * 8) =
                *(const uint4*)(Cs + row * 136 + chunk * 8);
    }
}

__global__ __launch_bounds__(256) void finalize_gemm0(const u32* __restrict__ cursor,
                                                      const u32* __restrict__ edgeBuf,
                                                      int2* __restrict__ rowse, int* __restrict__ col_idx,
                                                      int nbuck,
                                                      const float* __restrict__ A, const u16* __restrict__ Wp,
                                                      u16* __restrict__ outb, int N) {
    __shared__ u16 Cs[64 * 136];
    const int tid = threadIdx.x;
    if ((int)blockIdx.x < nbuck) {
        // ---- csr finalize for bucket b ----
        int* hist = (int*)Cs;            // 128 ints
        int* lcur = ((int*)Cs) + 128;    // 128 ints
        const int b = blockIdx.x;
        const size_t sbase = (size_t)b << 12;
        int c[4];
        #pragma unroll
        for (int s = 0; s < 4; s++) c[s] = min((int)cursor[b * 4 + s], CAPS);
        if (tid < 128) hist[tid] = 0;
        __syncthreads();
        #pragma unroll
        for (int s = 0; s < 4; s++)
            for (int i = tid; i < c[s]; i += 256)
                atomicAdd(&hist[edgeBuf[sbase + (s << 10) + i] >> 20], 1);
        __syncthreads();
        if (tid < 64) {
            int v0 = hist[tid * 2], v1 = hist[tid * 2 + 1];
            int s = v0 + v1;
            int incl = s;
            #pragma unroll
            for (int off = 1; off < 64; off <<= 1) { int t = __shfl_up(incl, off); if (tid >= off) incl += t; }
            int excl = incl - s;
            lcur[tid * 2] = excl;
            lcur[tid * 2 + 1] = excl + v0;
            int node = b * 128 + tid * 2;
            int st = (int)sbase + excl;
            if (node < N) rowse[node] = make_int2(st, st + v0);
            if (node + 1 < N) rowse[node + 1] = make_int2(st + v0, st + v0 + v1);
        }
        __syncthreads();
        #pragma unroll
        for (int s = 0; s < 4; s++)
            for (int i = tid; i < c[s]; i += 256) {
                u32 p = edgeBuf[sbase + (s << 10) + i];
                int pos = atomicAdd(&lcur[p >> 20], 1);
                col_idx[sbase + pos] = (int)(p & 0xFFFFFu);
            }
    } else {
        // ---- gemm layer 0 (fused fp32 -> bf16 cast) ----
        const int bid = blockIdx.x - nbuck;
        const int wave = tid >> 6, lane = tid & 63, quad = lane >> 4, l16 = lane & 15;
        const int row0 = bid * 64;
        const int arow = row0 + wave * 16 + l16;
        union { u32 u[4]; short8 s; } cv;
        short8 af[4];
        if (arow < N) {
            const float* ab = A + (size_t)arow * 128 + quad * 8;
            #pragma unroll
            for (int kt = 0; kt < 4; kt++) {
                float4 x0 = *(const float4*)(ab + kt * 32);
                float4 x1 = *(const float4*)(ab + kt * 32 + 4);
                cv.u[0] = pack_bf16x2(x0.x, x0.y);
                cv.u[1] = pack_bf16x2(x0.z, x0.w);
                cv.u[2] = pack_bf16x2(x1.x, x1.y);
                cv.u[3] = pack_bf16x2(x1.z, x1.w);
                af[kt] = cv.s;
            }
        } else {
            short8 z = {0, 0, 0, 0, 0, 0, 0, 0};
            #pragma unroll
            for (int kt = 0; kt < 4; kt++) af[kt] = z;
        }
        gemm_body(af, Wp, outb, N, row0, tid, wave, lane, quad, l16, Cs);
    }
}

// layer-1 GEMM: bf16 A
__global__ __launch_bounds__(256) void gemm_mfma(const u16* __restrict__ A, const u16* __restrict__ Wp,
                                                 u16* __restrict__ outb, int N) {
    __shared__ u16 Cs[64 * 136];
    const int tid = threadIdx.x;
    const int wave = tid >> 6, lane = tid & 63, quad = lane >> 4, l16 = lane & 15;
    const int row0 = blockIdx.x * 64;
    const int arow = row0 + wave * 16 + l16;
    short8 af[4];
    if (arow < N) {
        const u16* ab = A + (size_t)arow * 128 + quad * 8;
        #pragma unroll
        for (int kt = 0; kt < 4; kt++) af[kt] = *(const short8*)(ab + kt * 32);
    } else {
        short8 z = {0, 0, 0, 0, 0, 0, 0, 0};
        #pragma unroll
        for (int kt = 0; kt < 4; kt++) af[kt] = z;
    }
    gemm_body(af, Wp, outb, N, row0, tid, wave, lane, quad, l16, Cs);
}

// ---------------- aggregate: wave per node, 4 rows per vector instruction ----------------
// quarter q = lane>>4 handles edges 4k+q; lane holds 8 dims (uint4 of bf16); f32x2 accumulate
// (packed-add friendly); tail lanes gather the zero row (index N); cross-quarter shfl_xor reduce.
static __device__ __forceinline__ void add_row(f32x2* acc, uint4 u) {
    acc[0] += (f32x2){bf16lo_to_f32(u.x), bf16hi_to_f32(u.x)};
    acc[1] += (f32x2){bf16lo_to_f32(u.y), bf16hi_to_f32(u.y)};
    acc[2] += (f32x2){bf16lo_to_f32(u.z), bf16hi_to_f32(u.z)};
    acc[3] += (f32x2){bf16lo_to_f32(u.w), bf16hi_to_f32(u.w)};
}

__global__ __launch_bounds__(256) void agg_relu(const u16* __restrict__ xwb, const int2* __restrict__ rowse,
                                                const int* __restrict__ col_idx, const float* __restrict__ bias,
                                                u16* __restrict__ outh, int N) {
    int wid = (blockIdx.x * 256 + threadIdx.x) >> 6;
    int lane = threadIdx.x & 63;
    if (wid >= N) return;
    const int q = lane >> 4;
    const int d8 = (lane & 15) * 8;
    f32x2 acc[4];
    #pragma unroll
    for (int t = 0; t < 4; t++) acc[t] = (f32x2){0.f, 0.f};
    int2 se = rowse[wid];
    int start = se.x, end = se.y;
    for (int e = start; e < end; e += 64) {
        int idx = e + lane;
        int j = (idx < end) ? col_idx[idx] : N;   // tail -> shared zero row
        int cnt = min(64, end - e);
        for (int i = 0; i < cnt; i += 16) {
            int j0 = __shfl(j, i + q);
            int j1 = __shfl(j, i + 4 + q);
            int j2 = __shfl(j, i + 8 + q);
            int j3 = __shfl(j, i + 12 + q);
            uint4 r0 = *(const uint4*)(xwb + (size_t)j0 * D + d8);
            uint4 r1 = *(const uint4*)(xwb + (size_t)j1 * D + d8);
            uint4 r2 = *(const uint4*)(xwb + (size_t)j2 * D + d8);
            uint4 r3 = *(const uint4*)(xwb + (size_t)j3 * D + d8);
            add_row(acc, r0);
            add_row(acc, r1);
            add_row(acc, r2);
            add_row(acc, r3);
        }
    }
    float av[8] = {acc[0].x, acc[0].y, acc[1].x, acc[1].y, acc[2].x, acc[2].y, acc[3].x, acc[3].y};
    #pragma unroll
    for (int t = 0; t < 8; t++) {
        av[t] += __shfl_xor(av[t], 16);
        av[t] += __shfl_xor(av[t], 32);
    }
    uint4 sv = *(const uint4*)(xwb + (size_t)wid * D + d8);
    float4 ba = *(const float4*)(bias + d8);
    float4 bb = *(const float4*)(bias + d8 + 4);
    float r[8];
    r[0] = fmaxf(av[0] + bf16lo_to_f32(sv.x) + ba.x, 0.f);
    r[1] = fmaxf(av[1] + bf16hi_to_f32(sv.x) + ba.y, 0.f);
    r[2] = fmaxf(av[2] + bf16lo_to_f32(sv.y) + ba.z, 0.f);
    r[3] = fmaxf(av[3] + bf16hi_to_f32(sv.y) + ba.w, 0.f);
    r[4] = fmaxf(av[4] + bf16lo_to_f32(sv.z) + bb.x, 0.f);
    r[5] = fmaxf(av[5] + bf16hi_to_f32(sv.z) + bb.y, 0.f);
    r[6] = fmaxf(av[6] + bf16lo_to_f32(sv.w) + bb.z, 0.f);
    r[7] = fmaxf(av[7] + bf16hi_to_f32(sv.w) + bb.w, 0.f);
    if (q == 0) {
        uint4 o;
        o.x = pack_bf16x2(r[0], r[1]);
        o.y = pack_bf16x2(r[2], r[3]);
        o.z = pack_bf16x2(r[4], r[5]);
        o.w = pack_bf16x2(r[6], r[7]);
        *(uint4*)(outh + (size_t)wid * D + d8) = o;
    }
}

// ---------------- fused head + per-graph mean: block per graph ----------------
__global__ __launch_bounds__(128) void head_mean(const u16* __restrict__ h, const float* __restrict__ Wf,
                                                 const float* __restrict__ bfv, const int* __restrict__ goff,
                                                 const int* __restrict__ gsize, float* __restrict__ out, int G) {
    __shared__ float Wl[128 * 12];
    __shared__ float bl[12];
    __shared__ float part[2][12];
    int tid = threadIdx.x;
    for (int i = tid; i < 128 * 12; i += 128) Wl[i] = Wf[i];
    if (tid < 12) bl[tid] = bfv[tid];
    __syncthreads();
    int g = blockIdx.x;
    int start = goff[g];
    int size = gsize[g];
    float sum[12];
    #pragma unroll
    for (int t = 0; t < 12; t++) sum[t] = 0.f;
    for (int n = tid; n < size; n += 128) {
        const u16* hr = h + (size_t)(start + n) * D;
        float acc[12];
        #pragma unroll
        for (int t = 0; t < 12; t++) acc[t] = bl[t];
        for (int k = 0; k < 128; k += 8) {
            uint4 u = *(const uint4*)(hr + k);
            float x[8];
            x[0] = bf16lo_to_f32(u.x); x[1] = bf16hi_to_f32(u.x);
            x[2] = bf16lo_to_f32(u.y); x[3] = bf16hi_to_f32(u.y);
            x[4] = bf16lo_to_f32(u.z); x[5] = bf16hi_to_f32(u.z);
            x[6] = bf16lo_to_f32(u.w); x[7] = bf16hi_to_f32(u.w);
            #pragma unroll
            for (int kk = 0; kk < 8; kk++) {
                const float* wr = Wl + (k + kk) * 12;
                #pragma unroll
                for (int t = 0; t < 12; t++) acc[t] += x[kk] * wr[t];
            }
        }
        #pragma unroll
        for (int t = 0; t < 12; t++) sum[t] += 1.f / (1.f + __expf(-acc[t]));
    }
    int lane = tid & 63, wv = tid >> 6;
    #pragma unroll
    for (int t = 0; t < 12; t++) {
        #pragma unroll
        for (int off = 32; off >= 1; off >>= 1) sum[t] += __shfl_xor(sum[t], off);
    }
    if (lane == 0) {
        #pragma unroll
        for (int t = 0; t < 12; t++) part[wv][t] = sum[t];
    }
    __syncthreads();
    if (tid < 12) out[(size_t)g * 12 + tid] = (part[0][tid] + part[1][tid]) / (float)size;
}

// ---------------- launch ----------------

extern "C" void kernel_launch(void* const* d_in, const int* in_sizes, int n_in,
                              void* d_out, int out_size, void* d_ws, size_t ws_size,
                              hipStream_t stream) {
    const float* X   = (const float*)d_in[0];
    const int* edges = (const int*)d_in[1];
    const int* gsz   = (const int*)d_in[2];
    const float* W0  = (const float*)d_in[3];
    const float* b0  = (const float*)d_in[4];
    const float* W1  = (const float*)d_in[5];
    const float* b1  = (const float*)d_in[6];
    const float* Wf  = (const float*)d_in[7];
    const float* bfv = (const float*)d_in[8];
    float* out = (float*)d_out;

    const int N = in_sizes[0] / D;       // 100000
    const int E = in_sizes[1] / 2;       // 1600000
    const int G = in_sizes[2];           // 1000
    const int* esrc = edges;
    const int* edst = edges + E;
    const int nbuck = (N + 127) >> 7;    // 782

    // workspace layout (xwb/hb get N+64 rows: row N is the zero pad row)
    char* ws = (char*)d_ws;
    char* p = ws;
    u16* xwb     = (u16*)p;  p += (((size_t)(N + 64) * D * 2) + 255) & ~255ull;
    u16* hb      = (u16*)p;  p += (((size_t)(N + 64) * D * 2) + 255) & ~255ull;
    u16* Wp0     = (u16*)p;  p += ((size_t)128 * 128 * 2 + 255) & ~255ull;
    u16* Wp1     = (u16*)p;  p += ((size_t)128 * 128 * 2 + 255) & ~255ull;
    u32* edgeBuf = (u32*)p;  p += (((size_t)nbuck * CAPB * 4) + 255) & ~255ull;   // 12.8 MB
    int* col_idx = (int*)p;  p += (((size_t)nbuck * CAPB * 4) + 255) & ~255ull;   // 12.8 MB
    int2* rowse  = (int2*)p; p += (((size_t)N * 8) + 255) & ~255ull;
    u32* cursor  = (u32*)p;  p += (((size_t)nbuck * 4 * 4) + 255) & ~255ull;
    int* goff    = (int*)p;

    // prep: goff scan + cursor zero + W0/W1 pack (one dispatch)
    prep<<<130, 256, 0, stream>>>(W0, W1, Wp0, Wp1, gsz, G, goff, cursor, nbuck * 4);

    // single-pass bucket placement (global atomic sub-cursors)
    bucket_place<<<512, 512, 0, stream>>>(esrc, edst, E, cursor, edgeBuf);

    // fused: per-bucket CSR finalize + layer-0 GEMM
    const int gemmGrid = (N + 63) / 64;
    finalize_gemm0<<<nbuck + gemmGrid, 256, 0, stream>>>(cursor, edgeBuf, rowse, col_idx, nbuck,
                                                         X, Wp0, xwb, N);
    agg_relu<<<(N * 64 + 255) / 256, 256, 0, stream>>>(xwb, rowse, col_idx, b0, hb, N);
    // layer 1
    gemm_mfma<<<gemmGrid, 256, 0, stream>>>(hb, Wp1, xwb, N);
    agg_relu<<<(N * 64 + 255) / 256, 256, 0, stream>>>(xwb, rowse, col_idx, b1, hb, N);
    // fused head + readout
    head_mean<<<G, 128, 0, stream>>>(hb, Wf, bfv, goff, gsz, out, G);
}

// Round 8
// 302.979 us; speedup vs baseline: 1.3728x; 1.3728x over previous
//
#include <hip/hip_runtime.h>
#include <math.h>

#define D 128
#define NBUCK_MAX 1024     // runtime nbuck = ceil(N/128) = 782
#define NB_EDGE   256      // edge-chunk blocks for count/placement passes

typedef unsigned short u16;
typedef unsigned int   u32;
typedef __attribute__((ext_vector_type(8))) short short8;   // 8 bf16 = 4 VGPRs (MFMA A/B frag)
typedef __attribute__((ext_vector_type(4))) float f32x4;    // MFMA C/D frag
typedef __attribute__((ext_vector_type(2))) float f32x2;

static __device__ __forceinline__ u16 f32_to_bf16(float f) {
    u32 u = __builtin_bit_cast(u32, f);
    u32 r = (u + 0x7FFFu + ((u >> 16) & 1u)) >> 16;          // RNE
    return (u16)r;
}
static __device__ __forceinline__ u32 pack_bf16x2(float lo, float hi) {
    return (u32)f32_to_bf16(lo) | ((u32)f32_to_bf16(hi) << 16);
}
static __device__ __forceinline__ float bf16lo_to_f32(u32 v) {
    return __builtin_bit_cast(float, v << 16);
}
static __device__ __forceinline__ float bf16hi_to_f32(u32 v) {
    return __builtin_bit_cast(float, v & 0xFFFF0000u);
}

// ---------------- prep: goff scan (block 0) + W pack (blocks 1..128) ----------------
// Wp[((nt*4+kt)*64 + lane)*8 + j] = bf16( W[kt*32 + (lane>>4)*8 + j][nt*16 + (lane&15)] )
__global__ __launch_bounds__(256) void prep(const float* __restrict__ W0, const float* __restrict__ W1,
                                            u16* __restrict__ Wp0, u16* __restrict__ Wp1,
                                            const int* __restrict__ gsz, int G, int* __restrict__ goff) {
    int b = blockIdx.x;
    int tid = threadIdx.x;
    if (b == 0) {
        __shared__ int wsum[4];
        int base = tid * 4;
        int v[4];
        #pragma unroll
        for (int k = 0; k < 4; k++) v[k] = (base + k < G) ? gsz[base + k] : 0;
        int s = v[0] + v[1] + v[2] + v[3];
        int lane = tid & 63;
        int incl = s;
        #pragma unroll
        for (int off = 1; off < 64; off <<= 1) { int t = __shfl_up(incl, off); if (lane >= off) incl += t; }
        int wv = tid >> 6;
        if (lane == 63) wsum[wv] = incl;
        __syncthreads();
        int woff = 0;
        for (int w = 0; w < wv; w++) woff += wsum[w];
        int run = woff + incl - s;
        #pragma unroll
        for (int k = 0; k < 4; k++) {
            if (base + k <= G) goff[base + k] = run;
            run += v[k];
        }
    } else {
        int gidx = (b - 1) * 256 + tid;                      // 0 .. 32767
        const float* W = (gidx < 128 * 128) ? W0 : W1;
        u16* Wp = (gidx < 128 * 128) ? Wp0 : Wp1;
        int idx = gidx & (128 * 128 - 1);
        int j = idx & 7, lane = (idx >> 3) & 63, kt = (idx >> 9) & 3, nt = idx >> 11;
        int k = kt * 32 + ((lane >> 4) << 3) + j;
        int n = nt * 16 + (lane & 15);
        Wp[idx] = f32_to_bf16(W[k * 128 + n]);
    }
}

// ---------------- bucketed edge grouping (atomic-free global placement) ----------------

__global__ __launch_bounds__(512) void bucket_count(const int* __restrict__ dst, int E, int nbuck,
                                                    int* __restrict__ blockHist) {
    __shared__ int h[NBUCK_MAX];
    int tid = threadIdx.x;
    for (int i = tid; i < nbuck; i += 512) h[i] = 0;
    __syncthreads();
    int per = (E + NB_EDGE - 1) / NB_EDGE;
    int s = blockIdx.x * per, e = min(E, s + per);
    for (int i = s + tid; i < e; i += 512) atomicAdd(&h[dst[i] >> 7], 1);
    __syncthreads();
    for (int i = tid; i < nbuck; i += 512) blockHist[blockIdx.x * nbuck + i] = h[i];
}

// per bucket (one wave): exclusive-scan its NB_EDGE per-block counts in place; emit total.
__global__ __launch_bounds__(256) void scan_blocks(int* __restrict__ blockHist, int nbuck,
                                                   int* __restrict__ bucketTotal) {
    int bucket = (blockIdx.x * 256 + threadIdx.x) >> 6;
    int lane = threadIdx.x & 63;
    if (bucket >= nbuck) return;
    int carry = 0;
    #pragma unroll
    for (int c = 0; c < NB_EDGE / 64; c++) {
        int idx = (c * 64 + lane) * nbuck + bucket;
        int v = blockHist[idx];
        int incl = v;
        #pragma unroll
        for (int off = 1; off < 64; off <<= 1) { int t = __shfl_up(incl, off); if (lane >= off) incl += t; }
        blockHist[idx] = carry + incl - v;
        carry += __shfl(incl, 63);
    }
    if (lane == 0) bucketTotal[bucket] = carry;
}

// single block: exclusive-scan bucket totals -> bucketBase[0..nbuck] (sentinel at nbuck)
__global__ __launch_bounds__(256) void scan_buckets(const int* __restrict__ bucketTotal, int nbuck,
                                                    int* __restrict__ bucketBase) {
    __shared__ int wsum[4];
    int tid = threadIdx.x;
    int base = tid * 4;
    int v[4];
    #pragma unroll
    for (int k = 0; k < 4; k++) v[k] = (base + k < nbuck) ? bucketTotal[base + k] : 0;
    int s = v[0] + v[1] + v[2] + v[3];
    int lane = tid & 63;
    int incl = s;
    #pragma unroll
    for (int off = 1; off < 64; off <<= 1) { int t = __shfl_up(incl, off); if (lane >= off) incl += t; }
    int wv = tid >> 6;
    if (lane == 63) wsum[wv] = incl;
    __syncthreads();
    int woff = 0;
    for (int w = 0; w < wv; w++) woff += wsum[w];
    int run = woff + incl - s;
    #pragma unroll
    for (int k = 0; k < 4; k++) {
        if (base + k <= nbuck) bucketBase[base + k] = run;
        run += v[k];
    }
}

// placement via LDS cursors: per (block,bucket) writes are sequential -> ~50% line utilization
__global__ __launch_bounds__(512) void bucket_place(const int* __restrict__ src, const int* __restrict__ dst,
                                                    int E, int nbuck, const int* __restrict__ blockHist,
                                                    const int* __restrict__ bucketBase,
                                                    u32* __restrict__ edgeBuf) {
    __shared__ int cur[NBUCK_MAX];
    int tid = threadIdx.x;
    for (int i = tid; i < nbuck; i += 512)
        cur[i] = bucketBase[i] + blockHist[blockIdx.x * nbuck + i];
    __syncthreads();
    int per = (E + NB_EDGE - 1) / NB_EDGE;
    int s = blockIdx.x * per, e = min(E, s + per);
    for (int i = s + tid; i < e; i += 512) {
        int d = dst[i];
        int b = d >> 7;
        int pos = atomicAdd(&cur[b], 1);
        edgeBuf[pos] = (u32)src[i] | ((u32)(d & 127) << 20);
    }
}

// ---------------- MFMA GEMM core ----------------
static __device__ __forceinline__ void gemm_body(const short8 af[4], const u16* __restrict__ Wp,
                                                 u16* __restrict__ outb, int N, int row0,
                                                 int tid, int wave, int lane, int quad, int l16,
                                                 u16* Cs) {
    f32x4 acc[8];
    #pragma unroll
    for (int nt = 0; nt < 8; nt++) acc[nt] = (f32x4){0.f, 0.f, 0.f, 0.f};
    #pragma unroll
    for (int kt = 0; kt < 4; kt++) {
        #pragma unroll
        for (int nt = 0; nt < 8; nt++) {
            short8 bf = *(const short8*)(Wp + ((size_t)(nt * 4 + kt) * 64 + lane) * 8);
            acc[nt] = __builtin_amdgcn_mfma_f32_16x16x32_bf16(af[kt], bf, acc[nt], 0, 0, 0);
        }
    }
    // C layout col=lane&15, row=quad*4+reg -> LDS transpose -> coalesced bf16 store
    #pragma unroll
    for (int nt = 0; nt < 8; nt++) {
        #pragma unroll
        for (int r = 0; r < 4; r++) {
            int rl = wave * 16 + quad * 4 + r;
            Cs[rl * 136 + nt * 16 + l16] = f32_to_bf16(acc[nt][r]);
        }
    }
    __syncthreads();
    for (int i = tid; i < 64 * 16; i += 256) {
        int row = i >> 4, chunk = i & 15;
        int grow = row0 + row;
        if (grow <= N)      // row N = zero pad row for agg tail lanes
            *(uint4*)(outb + (size_t)grow * 128 + chunk * 8) =
                *(const uint4*)(Cs + row * 136 + chunk * 8);
    }
}

// fused: csr finalize (blocks 0..nbuck-1) + layer-0 gemm w/ fp32->bf16 cast (blocks nbuck..)
__global__ __launch_bounds__(256) void finalize_gemm0(const u32* __restrict__ edgeBuf,
                                                      const int* __restrict__ bucketBase,
                                                      int2* __restrict__ rowse, int* __restrict__ col_idx,
                                                      int nbuck,
                                                      const float* __restrict__ A, const u16* __restrict__ Wp,
                                                      u16* __restrict__ outb, int N) {
    __shared__ u16 Cs[64 * 136];
    const int tid = threadIdx.x;
    if ((int)blockIdx.x < nbuck) {
        int* hist = (int*)Cs;            // 128 ints
        int* lcur = ((int*)Cs) + 128;    // 128 ints
        const int b = blockIdx.x;
        const int start = bucketBase[b], end = bucketBase[b + 1];
        if (tid < 128) hist[tid] = 0;
        __syncthreads();
        for (int i = start + tid; i < end; i += 256)
            atomicAdd(&hist[edgeBuf[i] >> 20], 1);
        __syncthreads();
        if (tid < 64) {
            int v0 = hist[tid * 2], v1 = hist[tid * 2 + 1];
            int s = v0 + v1;
            int incl = s;
            #pragma unroll
            for (int off = 1; off < 64; off <<= 1) { int t = __shfl_up(incl, off); if (tid >= off) incl += t; }
            int excl = incl - s;
            lcur[tid * 2] = excl;
            lcur[tid * 2 + 1] = excl + v0;
            int node = b * 128 + tid * 2;
            int st = start + excl;
            if (node < N) rowse[node] = make_int2(st, st + v0);
            if (node + 1 < N) rowse[node + 1] = make_int2(st + v0, st + v0 + v1);
        }
        __syncthreads();
        for (int i = start + tid; i < end; i += 256) {
            u32 p = edgeBuf[i];
            int pos = atomicAdd(&lcur[p >> 20], 1);
            col_idx[start + pos] = (int)(p & 0xFFFFFu);
        }
    } else {
        const int bid = blockIdx.x - nbuck;
        const int wave = tid >> 6, lane = tid & 63, quad = lane >> 4, l16 = lane & 15;
        const int row0 = bid * 64;
        const int arow = row0 + wave * 16 + l16;
        union { u32 u[4]; short8 s; } cv;
        short8 af[4];
        if (arow < N) {
            const float* ab = A + (size_t)arow * 128 + quad * 8;
            #pragma unroll
            for (int kt = 0; kt < 4; kt++) {
                float4 x0 = *(const float4*)(ab + kt * 32);
                float4 x1 = *(const float4*)(ab + kt * 32 + 4);
                cv.u[0] = pack_bf16x2(x0.x, x0.y);
                cv.u[1] = pack_bf16x2(x0.z, x0.w);
                cv.u[2] = pack_bf16x2(x1.x, x1.y);
                cv.u[3] = pack_bf16x2(x1.z, x1.w);
                af[kt] = cv.s;
            }
        } else {
            short8 z = {0, 0, 0, 0, 0, 0, 0, 0};
            #pragma unroll
            for (int kt = 0; kt < 4; kt++) af[kt] = z;
        }
        gemm_body(af, Wp, outb, N, row0, tid, wave, lane, quad, l16, Cs);
    }
}

// layer-1 GEMM: bf16 A
__global__ __launch_bounds__(256) void gemm_mfma(const u16* __restrict__ A, const u16* __restrict__ Wp,
                                                 u16* __restrict__ outb, int N) {
    __shared__ u16 Cs[64 * 136];
    const int tid = threadIdx.x;
    const int wave = tid >> 6, lane = tid & 63, quad = lane >> 4, l16 = lane & 15;
    const int row0 = blockIdx.x * 64;
    const int arow = row0 + wave * 16 + l16;
    short8 af[4];
    if (arow < N) {
        const u16* ab = A + (size_t)arow * 128 + quad * 8;
        #pragma unroll
        for (int kt = 0; kt < 4; kt++) af[kt] = *(const short8*)(ab + kt * 32);
    } else {
        short8 z = {0, 0, 0, 0, 0, 0, 0, 0};
        #pragma unroll
        for (int kt = 0; kt < 4; kt++) af[kt] = z;
    }
    gemm_body(af, Wp, outb, N, row0, tid, wave, lane, quad, l16, Cs);
}

// ---------------- aggregate: wave per node, 4 rows per vector instruction ----------------
static __device__ __forceinline__ void add_row(f32x2* acc, uint4 u) {
    acc[0] += (f32x2){bf16lo_to_f32(u.x), bf16hi_to_f32(u.x)};
    acc[1] += (f32x2){bf16lo_to_f32(u.y), bf16hi_to_f32(u.y)};
    acc[2] += (f32x2){bf16lo_to_f32(u.z), bf16hi_to_f32(u.z)};
    acc[3] += (f32x2){bf16lo_to_f32(u.w), bf16hi_to_f32(u.w)};
}

__global__ __launch_bounds__(256) void agg_relu(const u16* __restrict__ xwb, const int2* __restrict__ rowse,
                                                const int* __restrict__ col_idx, const float* __restrict__ bias,
                                                u16* __restrict__ outh, int N) {
    int wid = (blockIdx.x * 256 + threadIdx.x) >> 6;
    int lane = threadIdx.x & 63;
    if (wid >= N) return;
    const int q = lane >> 4;
    const int d8 = (lane & 15) * 8;
    f32x2 acc[4];
    #pragma unroll
    for (int t = 0; t < 4; t++) acc[t] = (f32x2){0.f, 0.f};
    int2 se = rowse[wid];
    int start = se.x, end = se.y;
    for (int e = start; e < end; e += 64) {
        int idx = e + lane;
        int j = (idx < end) ? col_idx[idx] : N;   // tail -> shared zero row
        int cnt = min(64, end - e);
        for (int i = 0; i < cnt; i += 16) {
            int j0 = __shfl(j, i + q);
            int j1 = __shfl(j, i + 4 + q);
            int j2 = __shfl(j, i + 8 + q);
            int j3 = __shfl(j, i + 12 + q);
            uint4 r0 = *(const uint4*)(xwb + (size_t)j0 * D + d8);
            uint4 r1 = *(const uint4*)(xwb + (size_t)j1 * D + d8);
            uint4 r2 = *(const uint4*)(xwb + (size_t)j2 * D + d8);
            uint4 r3 = *(const uint4*)(xwb + (size_t)j3 * D + d8);
            add_row(acc, r0);
            add_row(acc, r1);
            add_row(acc, r2);
            add_row(acc, r3);
        }
    }
    float av[8] = {acc[0].x, acc[0].y, acc[1].x, acc[1].y, acc[2].x, acc[2].y, acc[3].x, acc[3].y};
    #pragma unroll
    for (int t = 0; t < 8; t++) {
        av[t] += __shfl_xor(av[t], 16);
        av[t] += __shfl_xor(av[t], 32);
    }
    uint4 sv = *(const uint4*)(xwb + (size_t)wid * D + d8);
    float4 ba = *(const float4*)(bias + d8);
    float4 bb = *(const float4*)(bias + d8 + 4);
    float r[8];
    r[0] = fmaxf(av[0] + bf16lo_to_f32(sv.x) + ba.x, 0.f);
    r[1] = fmaxf(av[1] + bf16hi_to_f32(sv.x) + ba.y, 0.f);
    r[2] = fmaxf(av[2] + bf16lo_to_f32(sv.y) + ba.z, 0.f);
    r[3] = fmaxf(av[3] + bf16hi_to_f32(sv.y) + ba.w, 0.f);
    r[4] = fmaxf(av[4] + bf16lo_to_f32(sv.z) + bb.x, 0.f);
    r[5] = fmaxf(av[5] + bf16hi_to_f32(sv.z) + bb.y, 0.f);
    r[6] = fmaxf(av[6] + bf16lo_to_f32(sv.w) + bb.z, 0.f);
    r[7] = fmaxf(av[7] + bf16hi_to_f32(sv.w) + bb.w, 0.f);
    if (q == 0) {
        uint4 o;
        o.x = pack_bf16x2(r[0], r[1]);
        o.y = pack_bf16x2(r[2], r[3]);
        o.z = pack_bf16x2(r[4], r[5]);
        o.w = pack_bf16x2(r[6], r[7]);
        *(uint4*)(outh + (size_t)wid * D + d8) = o;
    }
}

// ---------------- fused head + per-graph mean: block per graph ----------------
__global__ __launch_bounds__(128) void head_mean(const u16* __restrict__ h, const float* __restrict__ Wf,
                                                 const float* __restrict__ bfv, const int* __restrict__ goff,
                                                 const int* __restrict__ gsize, float* __restrict__ out, int G) {
    __shared__ float Wl[128 * 12];
    __shared__ float bl[12];
    __shared__ float part[2][12];
    int tid = threadIdx.x;
    for (int i = tid; i < 128 * 12; i += 128) Wl[i] = Wf[i];
    if (tid < 12) bl[tid] = bfv[tid];
    __syncthreads();
    int g = blockIdx.x;
    int start = goff[g];
    int size = gsize[g];
    float sum[12];
    #pragma unroll
    for (int t = 0; t < 12; t++) sum[t] = 0.f;
    for (int n = tid; n < size; n += 128) {
        const u16* hr = h + (size_t)(start + n) * D;
        float acc[12];
        #pragma unroll
        for (int t = 0; t < 12; t++) acc[t] = bl[t];
        for (int k = 0; k < 128; k += 8) {
            uint4 u = *(const uint4*)(hr + k);
            float x[8];
            x[0] = bf16lo_to_f32(u.x); x[1] = bf16hi_to_f32(u.x);
            x[2] = bf16lo_to_f32(u.y); x[3] = bf16hi_to_f32(u.y);
            x[4] = bf16lo_to_f32(u.z); x[5] = bf16hi_to_f32(u.z);
            x[6] = bf16lo_to_f32(u.w); x[7] = bf16hi_to_f32(u.w);
            #pragma unroll
            for (int kk = 0; kk < 8; kk++) {
                const float* wr = Wl + (k + kk) * 12;
                #pragma unroll
                for (int t = 0; t < 12; t++) acc[t] += x[kk] * wr[t];
            }
        }
        #pragma unroll
        for (int t = 0; t < 12; t++) sum[t] += 1.f / (1.f + __expf(-acc[t]));
    }
    int lane = tid & 63, wv = tid >> 6;
    #pragma unroll
    for (int t = 0; t < 12; t++) {
        #pragma unroll
        for (int off = 32; off >= 1; off >>= 1) sum[t] += __shfl_xor(sum[t], off);
    }
    if (lane == 0) {
        #pragma unroll
        for (int t = 0; t < 12; t++) part[wv][t] = sum[t];
    }
    __syncthreads();
    if (tid < 12) out[(size_t)g * 12 + tid] = (part[0][tid] + part[1][tid]) / (float)size;
}

// ---------------- launch ----------------

extern "C" void kernel_launch(void* const* d_in, const int* in_sizes, int n_in,
                              void* d_out, int out_size, void* d_ws, size_t ws_size,
                              hipStream_t stream) {
    const float* X   = (const float*)d_in[0];
    const int* edges = (const int*)d_in[1];
    const int* gsz   = (const int*)d_in[2];
    const float* W0  = (const float*)d_in[3];
    const float* b0  = (const float*)d_in[4];
    const float* W1  = (const float*)d_in[5];
    const float* b1  = (const float*)d_in[6];
    const float* Wf  = (const float*)d_in[7];
    const float* bfv = (const float*)d_in[8];
    float* out = (float*)d_out;

    const int N = in_sizes[0] / D;       // 100000
    const int E = in_sizes[1] / 2;       // 1600000
    const int G = in_sizes[2];           // 1000
    const int* esrc = edges;
    const int* edst = edges + E;
    const int nbuck = (N + 127) >> 7;    // 782

    // workspace layout (xwb/hb get N+64 rows: row N is the zero pad row)
    char* ws = (char*)d_ws;
    char* p = ws;
    u16* xwb     = (u16*)p;  p += (((size_t)(N + 64) * D * 2) + 255) & ~255ull;
    u16* hb      = (u16*)p;  p += (((size_t)(N + 64) * D * 2) + 255) & ~255ull;
    u16* Wp0     = (u16*)p;  p += ((size_t)128 * 128 * 2 + 255) & ~255ull;
    u16* Wp1     = (u16*)p;  p += ((size_t)128 * 128 * 2 + 255) & ~255ull;
    u32* edgeBuf = (u32*)p;  p += (((size_t)E * 4) + 255) & ~255ull;
    int* col_idx = (int*)p;  p += (((size_t)E * 4) + 255) & ~255ull;
    int2* rowse  = (int2*)p; p += (((size_t)N * 8) + 255) & ~255ull;
    int* blockHist   = (int*)p; p += ((size_t)NB_EDGE * NBUCK_MAX * 4 + 255) & ~255ull;
    int* bucketTotal = (int*)p; p += ((size_t)NBUCK_MAX * 4 + 255) & ~255ull;
    int* bucketBase  = (int*)p; p += ((size_t)(NBUCK_MAX + 1) * 4 + 255) & ~255ull;
    int* goff        = (int*)p;

    // prep: goff scan + W0/W1 pack (one dispatch)
    prep<<<129, 256, 0, stream>>>(W0, W1, Wp0, Wp1, gsz, G, goff);

    // edge grouping (atomic-free global placement)
    bucket_count<<<NB_EDGE, 512, 0, stream>>>(edst, E, nbuck, blockHist);
    scan_blocks<<<(nbuck * 64 + 255) / 256, 256, 0, stream>>>(blockHist, nbuck, bucketTotal);
    scan_buckets<<<1, 256, 0, stream>>>(bucketTotal, nbuck, bucketBase);
    bucket_place<<<NB_EDGE, 512, 0, stream>>>(esrc, edst, E, nbuck, blockHist, bucketBase, edgeBuf);

    // fused: per-bucket CSR finalize + layer-0 GEMM (fp32 A, fused cast)
    const int gemmGrid = (N + 63) / 64;
    finalize_gemm0<<<nbuck + gemmGrid, 256, 0, stream>>>(edgeBuf, bucketBase, rowse, col_idx, nbuck,
                                                         X, Wp0, xwb, N);
    agg_relu<<<(N * 64 + 255) / 256, 256, 0, stream>>>(xwb, rowse, col_idx, b0, hb, N);
    // layer 1
    gemm_mfma<<<gemmGrid, 256, 0, stream>>>(hb, Wp1, xwb, N);
    agg_relu<<<(N * 64 + 255) / 256, 256, 0, stream>>>(xwb, rowse, col_idx, b1, hb, N);
    // fused head + readout
    head_mean<<<G, 128, 0, stream>>>(hb, Wf, bfv, goff, gsz, out, G);
}